// Round 4
// baseline (9471.732 us; speedup 1.0000x reference)
//
#include <hip/hip_runtime.h>
#include <hip/hip_fp16.h>

#define TCH 256
#define NCH 4

typedef __attribute__((ext_vector_type(8))) _Float16 half8;
typedef __attribute__((ext_vector_type(4))) float floatx4;

__device__ __forceinline__ float sigm_f(float x) {
  return __frcp_rn(1.f + __expf(-x));
}
__device__ __forceinline__ float tanh_f(float x) {
  return fmaf(2.f, __frcp_rn(1.f + __expf(-2.f * x)), -1.f);
}

// ---------------- GEMM: C[m,n] = A[m,:] . B[n,:]  (B row-major [N][K], fp32)
template<bool AF32, bool RELUB>
__global__ __launch_bounds__(256, 2) void gemm_k(
    const void* __restrict__ Ab, const float* __restrict__ Bw,
    const float* __restrict__ bias, __half* __restrict__ C,
    const int* __restrict__ length, int K, int KT, int N, int arst, int t0)
{
  int b = blockIdx.x >> 1;
  int tloc0 = (blockIdx.x & 1) << 7;
  if (t0 + tloc0 >= length[b]) return;

  __shared__ half8 As[128][5];
  __shared__ half8 Bs[128][5];

  int tid = threadIdx.x;
  int wave = tid >> 6, lane = tid & 63;
  int wm = (wave & 1) << 6, wn = (wave >> 1) << 6;
  int quad = lane >> 4, sub = lane & 15;
  int n0 = blockIdx.y << 7;

  floatx4 acc[4][4];
#pragma unroll
  for (int i = 0; i < 4; ++i)
#pragma unroll
    for (int j = 0; j < 4; ++j)
#pragma unroll
      for (int e = 0; e < 4; ++e) acc[i][j][e] = 0.f;

  size_t arowbase = (size_t)b * arst + tloc0;

  for (int kt = 0; kt < KT; ++kt) {
    int k0 = kt << 5;
#pragma unroll
    for (int pass = 0; pass < 2; ++pass) {
      int idx = tid + (pass << 8);
      int r = idx >> 2, c8 = (idx & 3) << 3;
      int kb = k0 + c8;
      half8 v;
      if (AF32) {
        const float* src = (const float*)Ab + (arowbase + r) * K + kb;
        if (kb + 8 <= K) {
          float4 u0 = *(const float4*)(src);
          float4 u1 = *(const float4*)(src + 4);
          v[0] = (_Float16)u0.x; v[1] = (_Float16)u0.y; v[2] = (_Float16)u0.z; v[3] = (_Float16)u0.w;
          v[4] = (_Float16)u1.x; v[5] = (_Float16)u1.y; v[6] = (_Float16)u1.z; v[7] = (_Float16)u1.w;
        } else {
#pragma unroll
          for (int i = 0; i < 8; ++i) v[i] = (kb + i < K) ? (_Float16)src[i] : (_Float16)0.f;
        }
      } else {
        const __half* src = (const __half*)Ab + (arowbase + r) * K + kb;
        if (kb + 8 <= K) v = *(const half8*)src;
        else {
#pragma unroll
          for (int i = 0; i < 8; ++i) v[i] = (kb + i < K) ? *(const _Float16*)(src + i) : (_Float16)0.f;
        }
      }
      As[r][c8 >> 3] = v;
      const float* bsrc = Bw + (size_t)(n0 + r) * K + kb;
      half8 w;
      if (kb + 8 <= K) {
        float4 u0 = *(const float4*)(bsrc);
        float4 u1 = *(const float4*)(bsrc + 4);
        w[0] = (_Float16)u0.x; w[1] = (_Float16)u0.y; w[2] = (_Float16)u0.z; w[3] = (_Float16)u0.w;
        w[4] = (_Float16)u1.x; w[5] = (_Float16)u1.y; w[6] = (_Float16)u1.z; w[7] = (_Float16)u1.w;
      } else {
#pragma unroll
        for (int i = 0; i < 8; ++i) w[i] = (kb + i < K) ? (_Float16)bsrc[i] : (_Float16)0.f;
      }
      Bs[r][c8 >> 3] = w;
    }
    __syncthreads();
    half8 af[4], bf[4];
#pragma unroll
    for (int i = 0; i < 4; ++i) {
      af[i] = As[wm + (i << 4) + sub][quad];
      bf[i] = Bs[wn + (i << 4) + sub][quad];
    }
#pragma unroll
    for (int mt = 0; mt < 4; ++mt)
#pragma unroll
      for (int nt = 0; nt < 4; ++nt)
        acc[mt][nt] = __builtin_amdgcn_mfma_f32_16x16x32_f16(af[mt], bf[nt], acc[mt][nt], 0, 0, 0);
    __syncthreads();
  }
  size_t mrowbase = (size_t)blockIdx.x << 7;
#pragma unroll
  for (int nt = 0; nt < 4; ++nt) {
    int n = n0 + wn + (nt << 4) + sub;
    float bv = 0.f;
    if (RELUB) bv = bias[n];
#pragma unroll
    for (int mt = 0; mt < 4; ++mt) {
#pragma unroll
      for (int r4 = 0; r4 < 4; ++r4) {
        int m = wm + (mt << 4) + (quad << 2) + r4;
        float v = acc[mt][nt][r4] + bv;
        if (RELUB) v = fmaxf(v, 0.f);
        C[(mrowbase + m) * (size_t)N + n] = __float2half(v);
      }
    }
  }
}

// ---------------- weight prep: pack whh f32 -> f16 pairs, [layer][row][128 pairs]
__global__ __launch_bounds__(256, 4) void prep_k(
    const float* __restrict__ w0, const float* __restrict__ w1,
    const float* __restrict__ w2, unsigned* __restrict__ wpk)
{
  int g = blockIdx.x * 256 + threadIdx.x;      // 3*131072 total
  int l = g >> 17, rem = g & 131071;
  const float* src = (l == 0) ? w0 : (l == 1) ? w1 : w2;
  float2 f = *(const float2*)(src + ((size_t)rem << 1));
  wpk[g] = ((unsigned)__half_as_ushort(__float2half(f.y)) << 16)
         | (unsigned)__half_as_ushort(__float2half(f.x));
}

// ---------------- LSTM scan v4: MFMA, group=16 batches, 4 WGs/group (same XCD).
// WG slot owns h-dims [64*slot, 64*slot+64) for all 4 gates (256 gate-cols).
// W_hh slice register-resident as B-frags (64 VGPR/wave). h all-to-all among
// the 4 slots via tagged 8B relaxed atomics, mod-3 buffered (overwrite-safe).
// blockIdx = slot*8 + g -> group's 4 WGs share XCD (round-robin heuristic).
__global__ __launch_bounds__(512, 1) void scan4_k(
    const __half* __restrict__ xg, const unsigned* __restrict__ wpk,
    const float* __restrict__ bih, const float* __restrict__ bhh,
    __half* __restrict__ hout, unsigned* __restrict__ hstate,
    float* __restrict__ cstate, unsigned long long* __restrict__ exc,
    const int* __restrict__ length, int t0)
{
  const int g = blockIdx.x & 7, slot = blockIdx.x >> 3;
  const int b0 = g << 4;
  int maxlen = 0;
#pragma unroll
  for (int i = 0; i < 16; ++i) maxlen = max(maxlen, length[b0 + i]);
  const int tend = min(t0 + TCH, maxlen);
  if (t0 >= tend) return;

  const int tid = threadIdx.x;
  const int wave = tid >> 6, lane = tid & 63;
  const int quad = lane >> 4, sub = lane & 15;

  __shared__ __align__(16) __half h_lds[16][264];   // [batch][dim 0..255], pad
  __shared__ __align__(16) __half xgl[16][264];     // [batch][gate-col 0..255]
  __shared__ __align__(16) float gbuf[256 * 20];    // [gate-col][batch], pad 20

  // ---- register-resident W_hh B-frags: wave w owns n-tiles {2w, 2w+1}
  half8 wB[8][2];
  float bias2[2];
#pragma unroll
  for (int u = 0; u < 2; ++u) {
    int nt = (wave << 1) + u;
    int gate = nt >> 2;
    int d = ((nt << 4) + sub) & 63;
    int gr = (gate << 8) + (slot << 6) + d;       // global gate-row
    bias2[u] = bih[gr] + bhh[gr];
    const uint4* wp = (const uint4*)(wpk + ((size_t)gr << 7));
#pragma unroll
    for (int kt = 0; kt < 8; ++kt)
      wB[kt][u] = __builtin_bit_cast(half8, wp[(kt << 2) + quad]);
  }

  // ---- staging identity (xg + h_lds init): thread -> (batch xb, 8-half grp xq)
  const int xb = tid >> 5, xq = tid & 31;
  const __half* xsrc = xg + ((size_t)(b0 + xb) * TCH) * 1024
                       + ((xq >> 3) << 8) + (slot << 6) + ((xq & 7) << 3);
  // ---- updater identity: (batch ub, dim pair d0,d0+1), local dims of slot
  const int ub = tid >> 5, dp = tid & 31, d0 = dp << 1;
  float2 cc = make_float2(0.f, 0.f);
  unsigned pklast = 0;
  if (t0 > 0) {
    cc = *(const float2*)&cstate[(size_t)((b0 + ub) << 8) + (slot << 6) + d0];
    uint4 hv = *(const uint4*)&hstate[((size_t)(b0 + xb) << 7) + (xq << 2)];
    *(uint4*)&h_lds[xb][xq << 3] = hv;
  } else {
    uint4 z = {0u, 0u, 0u, 0u};
    *(uint4*)&h_lds[xb][xq << 3] = z;
  }

  // ---- poll identity: threads 0..383, peer p -> 4 tagged words
  const int pp = tid >> 7;                         // 0..2 (tid<384)
  const int ps = pp + (pp >= slot);                // peer slot
  const int jw = (tid & 127) << 2;                 // word base 0..508
  const unsigned long long* exrd =
      exc + ((size_t)((g << 2) + ps) * 3) * 512 + jw;
  unsigned long long* exwr = exc + ((size_t)((g << 2) + slot) * 3) * 512 + tid;

  for (int t = t0; t < tend; ++t) {
    const int tl = t - t0;
    // xg load first (global latency overlaps poll)
    uint4 xv = *(const uint4*)(xsrc + ((size_t)tl << 10));
    if (t > t0 && tid < 384) {
      const unsigned long long* src = exrd + (unsigned)(t % 3) * 512;
      unsigned long long w0, w1, w2, w3;
      for (;;) {
        w0 = __hip_atomic_load(src + 0, __ATOMIC_RELAXED, __HIP_MEMORY_SCOPE_AGENT);
        w1 = __hip_atomic_load(src + 1, __ATOMIC_RELAXED, __HIP_MEMORY_SCOPE_AGENT);
        w2 = __hip_atomic_load(src + 2, __ATOMIC_RELAXED, __HIP_MEMORY_SCOPE_AGENT);
        w3 = __hip_atomic_load(src + 3, __ATOMIC_RELAXED, __HIP_MEMORY_SCOPE_AGENT);
        if (((unsigned)(w0 >> 32) == (unsigned)t) &
            ((unsigned)(w1 >> 32) == (unsigned)t) &
            ((unsigned)(w2 >> 32) == (unsigned)t) &
            ((unsigned)(w3 >> 32) == (unsigned)t)) break;
        __builtin_amdgcn_s_sleep(1);
      }
      uint4 st;
      st.x = (unsigned)w0; st.y = (unsigned)w1; st.z = (unsigned)w2; st.w = (unsigned)w3;
      *(uint4*)&h_lds[jw >> 5][(ps << 6) + ((jw & 31) << 1)] = st;
    }
    *(uint4*)&xgl[xb][xq << 3] = xv;
    __syncthreads();

    // ---- MFMA: gates[16 b][256 gc] = h[16][256] @ Wslice^T
    floatx4 a0 = {0.f, 0.f, 0.f, 0.f}, a1 = {0.f, 0.f, 0.f, 0.f};
#pragma unroll
    for (int kt = 0; kt < 8; ++kt) {
      half8 af = *(const half8*)&h_lds[sub][(kt << 5) + (quad << 3)];
      a0 = __builtin_amdgcn_mfma_f32_16x16x32_f16(af, wB[kt][0], a0, 0, 0, 0);
      a1 = __builtin_amdgcn_mfma_f32_16x16x32_f16(af, wB[kt][1], a1, 0, 0, 0);
    }
    // ---- epilogue: + xg + bias, nonlinearity (gate = wave>>1, uniform)
#pragma unroll
    for (int u = 0; u < 2; ++u) {
      floatx4 av = u ? a1 : a0;
      int gcol = (((wave << 1) + u) << 4) + sub;
      float4 o;
#pragma unroll
      for (int r = 0; r < 4; ++r) {
        int m = (quad << 2) + r;
        float pre = av[r] + bias2[u] + __half2float(xgl[m][gcol]);
        (&o.x)[r] = ((wave >> 1) == 2) ? tanh_f(pre) : sigm_f(pre);
      }
      *(float4*)&gbuf[gcol * 20 + (quad << 2)] = o;
    }
    __syncthreads();

    // ---- c/h update for (ub, d0..d0+1)
    float i0 = gbuf[(d0) * 20 + ub],        i1 = gbuf[(d0 + 1) * 20 + ub];
    float f0 = gbuf[(64 + d0) * 20 + ub],   f1 = gbuf[(65 + d0) * 20 + ub];
    float g0 = gbuf[(128 + d0) * 20 + ub],  g1 = gbuf[(129 + d0) * 20 + ub];
    float o0 = gbuf[(192 + d0) * 20 + ub],  o1 = gbuf[(193 + d0) * 20 + ub];
    cc.x = f0 * cc.x + i0 * g0;
    cc.y = f1 * cc.y + i1 * g1;
    float h0 = o0 * tanh_f(cc.x);
    float h1 = o1 * tanh_f(cc.y);
    unsigned pk = ((unsigned)__half_as_ushort(__float2half(h1)) << 16)
                | (unsigned)__half_as_ushort(__float2half(h0));
    pklast = pk;
    *(unsigned*)&h_lds[ub][(slot << 6) + d0] = pk;
    *(unsigned*)&hout[(((size_t)(b0 + ub) * TCH) + tl) * 256 + (slot << 6) + d0] = pk;
    __hip_atomic_store(exwr + (unsigned)((t + 1) % 3) * 512,
                       ((unsigned long long)(unsigned)(t + 1) << 32) | (unsigned long long)pk,
                       __ATOMIC_RELAXED, __HIP_MEMORY_SCOPE_AGENT);
    // next iter's h_lds/xgl writes are fenced by this iter's barriers.
  }
  hstate[((size_t)(b0 + ub) << 7) + (slot << 5) + dp] = pklast;
  *(float2*)&cstate[(size_t)((b0 + ub) << 8) + (slot << 6) + d0] = cc;
}

// ---------------- head: decision = h2 . Wd + bd, ragged-masked sum, final /len
__global__ __launch_bounds__(256, 2) void head_k(
    const __half* __restrict__ h2, const float* __restrict__ Wd,
    const float* __restrict__ bd, const int* __restrict__ length,
    float* __restrict__ dacc, float* __restrict__ out, int t0, int first, int last)
{
  int b = blockIdx.x, tid = threadIdx.x;
  int lane = tid & 63, wave = tid >> 6;
  int len = length[b];
  int tend = min(t0 + TCH, len);
  float4 w4 = *(const float4*)(Wd + (lane << 2));
  float wsum = 0.f;
  for (int t = t0 + wave; t < tend; t += 4) {
    const __half* hr = h2 + (((size_t)b * TCH) + (t - t0)) * 256 + (lane << 2);
    uint2 u = *(const uint2*)hr;
    __half2 p0 = __builtin_bit_cast(__half2, u.x);
    __half2 p1 = __builtin_bit_cast(__half2, u.y);
    float s = w4.x * __half2float(p0.x) + w4.y * __half2float(p0.y)
            + w4.z * __half2float(p1.x) + w4.w * __half2float(p1.y);
#pragma unroll
    for (int off = 32; off > 0; off >>= 1) s += __shfl_xor(s, off);
    wsum += s;
  }
  __shared__ float wred[4];
  if (lane == 0) wred[wave] = wsum;
  __syncthreads();
  if (tid == 0) {
    int cnt = tend - t0; if (cnt < 0) cnt = 0;
    float tot = wred[0] + wred[1] + wred[2] + wred[3] + bd[0] * (float)cnt;
    if (!first) tot += dacc[b];
    dacc[b] = tot;
    if (last) out[b] = tot / (float)len;
  }
}

extern "C" void kernel_launch(void* const* d_in, const int* in_sizes, int n_in,
                              void* d_out, int out_size, void* d_ws, size_t ws_size,
                              hipStream_t stream) {
  (void)in_sizes; (void)n_in; (void)out_size; (void)ws_size;
  const float* x    = (const float*)d_in[0];
  const int* length = (const int*)d_in[1];
  const float* W1   = (const float*)d_in[2];
  const float* b1   = (const float*)d_in[3];
  const float* W2   = (const float*)d_in[4];
  const float* b2   = (const float*)d_in[5];
  const float* wih[3] = {(const float*)d_in[6],  (const float*)d_in[10], (const float*)d_in[14]};
  const float* whh[3] = {(const float*)d_in[7],  (const float*)d_in[11], (const float*)d_in[15]};
  const float* bih[3] = {(const float*)d_in[8],  (const float*)d_in[12], (const float*)d_in[16]};
  const float* bhh[3] = {(const float*)d_in[9],  (const float*)d_in[13], (const float*)d_in[17]};
  const float* Wd   = (const float*)d_in[18];
  const float* bd   = (const float*)d_in[19];
  float* out = (float*)d_out;

  char* ws = (char*)d_ws;
  __half* XG    = (__half*)(ws);                     // 32768 x 1024 f16 = 64 MiB
  __half* FEAT1 = (__half*)(ws + 67108864);          // 32768 x 256  f16 = 16 MiB
  __half* FEAT2 = (__half*)(ws + 83886080);          // 32768 x 512  f16 = 32 MiB
  __half* HBUF  = (__half*)(ws + 117440512);         // 32768 x 256  f16 = 16 MiB
  unsigned* WPK = (unsigned*)(ws + 134217728);       // 3 x 131072 u32 = 1.5 MiB
  unsigned long long* EXC = (unsigned long long*)(ws + 134217728 + 1572864);
                                                     // 3 x 49152 u64 = 1.125 MiB
  float* CST    = (float*)(ws + 134217728 + 1572864 + 1179648);      // 3 x 32768 f32
  unsigned* HST = (unsigned*)(ws + 134217728 + 1572864 + 1179648 + 393216);
                                                     // 3 x 16384 u32
  float* DACC   = (float*)(ws + 134217728 + 1572864 + 1179648 + 393216 + 196608);

  prep_k<<<1536, 256, 0, stream>>>(whh[0], whh[1], whh[2], WPK);

  for (int c = 0; c < NCH; ++c) {
    int t0 = c * TCH;
    gemm_k<true,  true ><<<dim3(256, 2), 256, 0, stream>>>(
        (const void*)(x + (size_t)t0 * 136), W1, b1, FEAT1, length, 136, 5, 256, 1024, t0);
    gemm_k<false, true ><<<dim3(256, 4), 256, 0, stream>>>(
        (const void*)FEAT1, W2, b2, FEAT2, length, 256, 8, 512, TCH, t0);
    gemm_k<false, false><<<dim3(256, 8), 256, 0, stream>>>(
        (const void*)FEAT2, wih[0], nullptr, XG, length, 512, 16, 1024, TCH, t0);
    scan4_k<<<32, 512, 0, stream>>>(XG, WPK, bih[0], bhh[0], HBUF,
                                    HST, CST, EXC, length, t0);
    gemm_k<false, false><<<dim3(256, 8), 256, 0, stream>>>(
        (const void*)HBUF, wih[1], nullptr, XG, length, 256, 8, 1024, TCH, t0);
    scan4_k<<<32, 512, 0, stream>>>(XG, WPK + 131072, bih[1], bhh[1], HBUF,
                                    HST + 16384, CST + 32768, EXC + 49152, length, t0);
    gemm_k<false, false><<<dim3(256, 8), 256, 0, stream>>>(
        (const void*)HBUF, wih[2], nullptr, XG, length, 256, 8, 1024, TCH, t0);
    scan4_k<<<32, 512, 0, stream>>>(XG, WPK + 262144, bih[2], bhh[2], HBUF,
                                    HST + 32768, CST + 65536, EXC + 98304, length, t0);
    head_k<<<128, 256, 0, stream>>>(HBUF, Wd, bd, length, DACC, out, t0, c == 0, c == NCH - 1);
  }
}

// Round 5
// 7738.965 us; speedup vs baseline: 1.2239x; 1.2239x over previous
//
#include <hip/hip_runtime.h>
#include <hip/hip_fp16.h>

#define TCH 256
#define NCH 4

typedef __attribute__((ext_vector_type(8))) _Float16 half8;
typedef __attribute__((ext_vector_type(2))) _Float16 half2v;
typedef __attribute__((ext_vector_type(4))) float floatx4;

__device__ __forceinline__ float dot2f(unsigned a, unsigned b, float c) {
  return __builtin_amdgcn_fdot2(__builtin_bit_cast(half2v, a),
                                __builtin_bit_cast(half2v, b), c, false);
}
__device__ __forceinline__ float sigm_f(float x) {
  return __frcp_rn(1.f + __expf(-x));
}
__device__ __forceinline__ float tanh_f(float x) {
  return fmaf(2.f, __frcp_rn(1.f + __expf(-2.f * x)), -1.f);
}

// ---------------- GEMM: C[m,n] = A[m,:] . B[n,:]  (B row-major [N][K], fp32)
template<bool AF32, bool RELUB>
__global__ __launch_bounds__(256, 2) void gemm_k(
    const void* __restrict__ Ab, const float* __restrict__ Bw,
    const float* __restrict__ bias, __half* __restrict__ C,
    const int* __restrict__ length, int K, int KT, int N, int arst, int t0)
{
  int b = blockIdx.x >> 1;
  int tloc0 = (blockIdx.x & 1) << 7;
  if (t0 + tloc0 >= length[b]) return;

  __shared__ half8 As[128][5];
  __shared__ half8 Bs[128][5];

  int tid = threadIdx.x;
  int wave = tid >> 6, lane = tid & 63;
  int wm = (wave & 1) << 6, wn = (wave >> 1) << 6;
  int quad = lane >> 4, sub = lane & 15;
  int n0 = blockIdx.y << 7;

  floatx4 acc[4][4];
#pragma unroll
  for (int i = 0; i < 4; ++i)
#pragma unroll
    for (int j = 0; j < 4; ++j)
#pragma unroll
      for (int e = 0; e < 4; ++e) acc[i][j][e] = 0.f;

  size_t arowbase = (size_t)b * arst + tloc0;

  for (int kt = 0; kt < KT; ++kt) {
    int k0 = kt << 5;
#pragma unroll
    for (int pass = 0; pass < 2; ++pass) {
      int idx = tid + (pass << 8);
      int r = idx >> 2, c8 = (idx & 3) << 3;
      int kb = k0 + c8;
      half8 v;
      if (AF32) {
        const float* src = (const float*)Ab + (arowbase + r) * K + kb;
        if (kb + 8 <= K) {
          float4 u0 = *(const float4*)(src);
          float4 u1 = *(const float4*)(src + 4);
          v[0] = (_Float16)u0.x; v[1] = (_Float16)u0.y; v[2] = (_Float16)u0.z; v[3] = (_Float16)u0.w;
          v[4] = (_Float16)u1.x; v[5] = (_Float16)u1.y; v[6] = (_Float16)u1.z; v[7] = (_Float16)u1.w;
        } else {
#pragma unroll
          for (int i = 0; i < 8; ++i) v[i] = (kb + i < K) ? (_Float16)src[i] : (_Float16)0.f;
        }
      } else {
        const __half* src = (const __half*)Ab + (arowbase + r) * K + kb;
        if (kb + 8 <= K) v = *(const half8*)src;
        else {
#pragma unroll
          for (int i = 0; i < 8; ++i) v[i] = (kb + i < K) ? *(const _Float16*)(src + i) : (_Float16)0.f;
        }
      }
      As[r][c8 >> 3] = v;
      const float* bsrc = Bw + (size_t)(n0 + r) * K + kb;
      half8 w;
      if (kb + 8 <= K) {
        float4 u0 = *(const float4*)(bsrc);
        float4 u1 = *(const float4*)(bsrc + 4);
        w[0] = (_Float16)u0.x; w[1] = (_Float16)u0.y; w[2] = (_Float16)u0.z; w[3] = (_Float16)u0.w;
        w[4] = (_Float16)u1.x; w[5] = (_Float16)u1.y; w[6] = (_Float16)u1.z; w[7] = (_Float16)u1.w;
      } else {
#pragma unroll
        for (int i = 0; i < 8; ++i) w[i] = (kb + i < K) ? (_Float16)bsrc[i] : (_Float16)0.f;
      }
      Bs[r][c8 >> 3] = w;
    }
    __syncthreads();
    half8 af[4], bf[4];
#pragma unroll
    for (int i = 0; i < 4; ++i) {
      af[i] = As[wm + (i << 4) + sub][quad];
      bf[i] = Bs[wn + (i << 4) + sub][quad];
    }
#pragma unroll
    for (int mt = 0; mt < 4; ++mt)
#pragma unroll
      for (int nt = 0; nt < 4; ++nt)
        acc[mt][nt] = __builtin_amdgcn_mfma_f32_16x16x32_f16(af[mt], bf[nt], acc[mt][nt], 0, 0, 0);
    __syncthreads();
  }
  size_t mrowbase = (size_t)blockIdx.x << 7;
#pragma unroll
  for (int nt = 0; nt < 4; ++nt) {
    int n = n0 + wn + (nt << 4) + sub;
    float bv = 0.f;
    if (RELUB) bv = bias[n];
#pragma unroll
    for (int mt = 0; mt < 4; ++mt) {
#pragma unroll
      for (int r4 = 0; r4 < 4; ++r4) {
        int m = wm + (mt << 4) + (quad << 2) + r4;
        float v = acc[mt][nt][r4] + bv;
        if (RELUB) v = fmaxf(v, 0.f);
        C[(mrowbase + m) * (size_t)N + n] = __float2half(v);
      }
    }
  }
}

// ---------------- weight prep: pack whh f32 -> f16 pairs.
// Pairs 0..95  -> WPKA[layer][row][96]            (register-resident part)
// Pairs 96..127-> WPKB[layer][chunk(8)][row(1024)][4 u32]  (LDS part, transposed
//                 so scan's ds_read_b128 has 16B lane stride = conflict-free)
__global__ __launch_bounds__(256, 4) void prep_k(
    const float* __restrict__ w0, const float* __restrict__ w1,
    const float* __restrict__ w2, unsigned* __restrict__ wpkA,
    unsigned* __restrict__ wpkB)
{
  int g = blockIdx.x * 256 + threadIdx.x;      // 3*131072 total pairs
  int l = g >> 17, rem = g & 131071;
  int r = rem >> 7, p = rem & 127;
  const float* src = (l == 0) ? w0 : (l == 1) ? w1 : w2;
  float2 f = *(const float2*)(src + ((size_t)rem << 1));
  unsigned pk = ((unsigned)__half_as_ushort(__float2half(f.y)) << 16)
              | (unsigned)__half_as_ushort(__float2half(f.x));
  if (p < 96) {
    wpkA[(size_t)l * 98304 + r * 96 + p] = pk;
  } else {
    int q = p - 96;                            // 0..31
    wpkB[(size_t)l * 32768 + (((q >> 2) << 10) + r) * 4 + (q & 3)] = pk;
  }
}

// ---------------- LSTM scan v5: single WG per batch element, 512 threads.
// Thread t owns gate-rows t and t+512. W_hh K[0,192) in 192 VGPRs (96 pairs x
// 2 rows); K[192,256) in LDS, transposed layout (conflict-free b128 reads).
// h broadcast via readlane. No cross-WG communication of any kind.
// __launch_bounds__(512,1): demand-driven VGPRs (~240), weights stay in VGPRs
// (the (512,2) variant capped at 128 and spilled weights to AGPRs - round 3).
__global__ __launch_bounds__(512, 1) void scan5_k(
    const __half* __restrict__ xg, const unsigned* __restrict__ wA,
    const uint4* __restrict__ wBt, const float* __restrict__ bih,
    const float* __restrict__ bhh, __half* __restrict__ hout,
    unsigned* __restrict__ hstate, float* __restrict__ cstate,
    const int* __restrict__ length, int t0)
{
  extern __shared__ char smem[];
  uint4* WL   = (uint4*)smem;                      // [8][1024] = 128 KB
  float* gbuf = (float*)(smem + 131072);           // [1024]
  __half* hh  = (__half*)(smem + 131072 + 4096);   // [256]

  const int b = blockIdx.x;
  const int len = length[b];
  const int tend = min(t0 + TCH, len);
  if (t0 >= tend) return;

  const int tid = threadIdx.x;
  const int lane = tid & 63;
  const int r0 = tid, r1 = tid + 512;

  // ---- stage LDS weight part (coalesced, layout already transposed)
  for (int i = tid; i < 8192; i += 512) WL[i] = wBt[i];

  // ---- register weight part
  unsigned w0[96], w1[96];
  {
    const uint4* p0 = (const uint4*)(wA + (size_t)r0 * 96);
    const uint4* p1 = (const uint4*)(wA + (size_t)r1 * 96);
#pragma unroll
    for (int i = 0; i < 24; ++i) {
      uint4 a = p0[i];
      w0[4*i] = a.x; w0[4*i+1] = a.y; w0[4*i+2] = a.z; w0[4*i+3] = a.w;
      uint4 c = p1[i];
      w1[4*i] = c.x; w1[4*i+1] = c.y; w1[4*i+2] = c.z; w1[4*i+3] = c.w;
    }
  }
  const float bias0 = bih[r0] + bhh[r0];
  const float bias1 = bih[r1] + bhh[r1];

  unsigned hp0 = 0, hp1 = 0;
  float cv = 0.f;
  if (t0 > 0) {
    hp0 = hstate[(b << 7) + lane];
    hp1 = hstate[(b << 7) + 64 + lane];
    if (tid < 256) cv = cstate[(b << 8) + tid];
  }
  __syncthreads();   // WL ready

  const __half* xgb = xg + (((size_t)b * TCH) << 10) + tid;
  float xv0 = __half2float(xgb[0]);
  float xv1 = __half2float(xgb[512]);

  for (int t = t0; t < tend; ++t) {
    const int tl = t - t0;
    const int tln = min(tl + 1, TCH - 1);
    __half nx0 = xgb[(size_t)tln << 10];          // next-step xg prefetch
    __half nx1 = xgb[((size_t)tln << 10) + 512];

    float a0[4] = {bias0 + xv0, 0.f, 0.f, 0.f};
    float a1[4] = {bias1 + xv1, 0.f, 0.f, 0.f};

    // LDS weight part first: ds_reads issue early, overlap the readlane stream
#pragma unroll
    for (int c = 0; c < 8; ++c) {
      uint4 q0 = WL[(c << 10) + r0];
      uint4 q1 = WL[(c << 10) + r1];
#pragma unroll
      for (int j = 0; j < 4; ++j) {
        unsigned rl = (unsigned)__builtin_amdgcn_readlane((int)hp1, 32 + (c << 2) + j);
        a0[j] = dot2f((&q0.x)[j], rl, a0[j]);
        a1[j] = dot2f((&q1.x)[j], rl, a1[j]);
      }
    }
    // register weight part: pairs 0..95 (one readlane serves both rows)
#pragma unroll
    for (int p = 0; p < 96; ++p) {
      unsigned rl = (unsigned)__builtin_amdgcn_readlane(
          (p < 64) ? (int)hp0 : (int)hp1, p & 63);
      a0[p & 3] = dot2f(w0[p], rl, a0[p & 3]);
      a1[p & 3] = dot2f(w1[p], rl, a1[p & 3]);
    }
    float pre0 = (a0[0] + a0[1]) + (a0[2] + a0[3]);
    float pre1 = (a1[0] + a1[1]) + (a1[2] + a1[3]);
    // r0: i (tid<256) or f -> sigmoid. r1: g (tid<256, tanh) or o (sigmoid).
    float g0 = sigm_f(pre0);
    float g1 = (tid < 256) ? tanh_f(pre1) : sigm_f(pre1);
    gbuf[r0] = g0;
    gbuf[r1] = g1;
    __syncthreads();
    if (tid < 256) {
      float iv = gbuf[tid], fv = gbuf[256 + tid];
      float gv = gbuf[512 + tid], ov = gbuf[768 + tid];
      cv = fv * cv + iv * gv;
      float hv = ov * tanh_f(cv);
      __half hx = __float2half(hv);
      hh[tid] = hx;
      hout[(((size_t)b * TCH) + tl) * 256 + tid] = hx;
    }
    __syncthreads();
    hp0 = ((const unsigned*)hh)[lane];
    hp1 = ((const unsigned*)hh)[64 + lane];
    xv0 = __half2float(nx0);
    xv1 = __half2float(nx1);
  }
  if (tid < 64)       hstate[(b << 7) + tid] = hp0;
  else if (tid < 128) hstate[(b << 7) + tid] = hp1;
  if (tid < 256) cstate[(b << 8) + tid] = cv;
}

// ---------------- head: decision = h2 . Wd + bd, ragged-masked sum, final /len
__global__ __launch_bounds__(256, 2) void head_k(
    const __half* __restrict__ h2, const float* __restrict__ Wd,
    const float* __restrict__ bd, const int* __restrict__ length,
    float* __restrict__ dacc, float* __restrict__ out, int t0, int first, int last)
{
  int b = blockIdx.x, tid = threadIdx.x;
  int lane = tid & 63, wave = tid >> 6;
  int len = length[b];
  int tend = min(t0 + TCH, len);
  float4 w4 = *(const float4*)(Wd + (lane << 2));
  float wsum = 0.f;
  for (int t = t0 + wave; t < tend; t += 4) {
    const __half* hr = h2 + (((size_t)b * TCH) + (t - t0)) * 256 + (lane << 2);
    uint2 u = *(const uint2*)hr;
    __half2 p0 = __builtin_bit_cast(__half2, u.x);
    __half2 p1 = __builtin_bit_cast(__half2, u.y);
    float s = w4.x * __half2float(p0.x) + w4.y * __half2float(p0.y)
            + w4.z * __half2float(p1.x) + w4.w * __half2float(p1.y);
#pragma unroll
    for (int off = 32; off > 0; off >>= 1) s += __shfl_xor(s, off);
    wsum += s;
  }
  __shared__ float wred[4];
  if (lane == 0) wred[wave] = wsum;
  __syncthreads();
  if (tid == 0) {
    int cnt = tend - t0; if (cnt < 0) cnt = 0;
    float tot = wred[0] + wred[1] + wred[2] + wred[3] + bd[0] * (float)cnt;
    if (!first) tot += dacc[b];
    dacc[b] = tot;
    if (last) out[b] = tot / (float)len;
  }
}

extern "C" void kernel_launch(void* const* d_in, const int* in_sizes, int n_in,
                              void* d_out, int out_size, void* d_ws, size_t ws_size,
                              hipStream_t stream) {
  (void)in_sizes; (void)n_in; (void)out_size; (void)ws_size;
  const float* x    = (const float*)d_in[0];
  const int* length = (const int*)d_in[1];
  const float* W1   = (const float*)d_in[2];
  const float* b1   = (const float*)d_in[3];
  const float* W2   = (const float*)d_in[4];
  const float* b2   = (const float*)d_in[5];
  const float* wih[3] = {(const float*)d_in[6],  (const float*)d_in[10], (const float*)d_in[14]};
  const float* whh[3] = {(const float*)d_in[7],  (const float*)d_in[11], (const float*)d_in[15]};
  const float* bih[3] = {(const float*)d_in[8],  (const float*)d_in[12], (const float*)d_in[16]};
  const float* bhh[3] = {(const float*)d_in[9],  (const float*)d_in[13], (const float*)d_in[17]};
  const float* Wd   = (const float*)d_in[18];
  const float* bd   = (const float*)d_in[19];
  float* out = (float*)d_out;

  char* ws = (char*)d_ws;
  __half* XG    = (__half*)(ws);                     // 32768 x 1024 f16 = 64 MiB
  __half* FEAT1 = (__half*)(ws + 67108864);          // 32768 x 256  f16 = 16 MiB
  __half* FEAT2 = (__half*)(ws + 83886080);          // 32768 x 512  f16 = 32 MiB
  __half* HBUF  = (__half*)(ws + 117440512);         // 32768 x 256  f16 = 16 MiB
  unsigned* WPKA = (unsigned*)(ws + 134217728);              // 3 x 98304 u32
  unsigned* WPKB = (unsigned*)(ws + 134217728 + 1179648);    // 3 x 32768 u32
  float* CST    = (float*)(ws + 134217728 + 1179648 + 393216);
  unsigned* HST = (unsigned*)(ws + 134217728 + 1179648 + 393216 + 393216);
  float* DACC   = (float*)(ws + 134217728 + 1179648 + 393216 + 393216 + 196608);

  (void)hipFuncSetAttribute((const void*)scan5_k,
      hipFuncAttributeMaxDynamicSharedMemorySize, 135680);
  const int SMEM = 131072 + 4096 + 512;

  prep_k<<<1536, 256, 0, stream>>>(whh[0], whh[1], whh[2], WPKA, WPKB);

  for (int c = 0; c < NCH; ++c) {
    int t0 = c * TCH;
    gemm_k<true,  true ><<<dim3(256, 2), 256, 0, stream>>>(
        (const void*)(x + (size_t)t0 * 136), W1, b1, FEAT1, length, 136, 5, 256, 1024, t0);
    gemm_k<false, true ><<<dim3(256, 4), 256, 0, stream>>>(
        (const void*)FEAT1, W2, b2, FEAT2, length, 256, 8, 512, TCH, t0);
    gemm_k<false, false><<<dim3(256, 8), 256, 0, stream>>>(
        (const void*)FEAT2, wih[0], nullptr, XG, length, 512, 16, 1024, TCH, t0);
    scan5_k<<<128, 512, SMEM, stream>>>(XG, WPKA, (const uint4*)WPKB,
                                        bih[0], bhh[0], HBUF, HST, CST, length, t0);
    gemm_k<false, false><<<dim3(256, 8), 256, 0, stream>>>(
        (const void*)HBUF, wih[1], nullptr, XG, length, 256, 8, 1024, TCH, t0);
    scan5_k<<<128, 512, SMEM, stream>>>(XG, WPKA + 98304, (const uint4*)(WPKB + 32768),
                                        bih[1], bhh[1], HBUF, HST + 16384, CST + 32768,
                                        length, t0);
    gemm_k<false, false><<<dim3(256, 8), 256, 0, stream>>>(
        (const void*)HBUF, wih[2], nullptr, XG, length, 256, 8, 1024, TCH, t0);
    scan5_k<<<128, 512, SMEM, stream>>>(XG, WPKA + 196608, (const uint4*)(WPKB + 65536),
                                        bih[2], bhh[2], HBUF, HST + 32768, CST + 65536,
                                        length, t0);
    head_k<<<128, 256, 0, stream>>>(HBUF, Wd, bd, length, DACC, out, t0, c == 0, c == NCH - 1);
  }
}